// Round 1
// baseline (1488.780 us; speedup 1.0000x reference)
//
#include <hip/hip_runtime.h>

// FP16(pulse bits, 16 floats of 0/1) -> FP8 E4M3 (pulse bits, 8 floats of 0/1).
// Purely memory-bound elementwise op: 64 B in + 32 B out per item, 16.7M items.
// One thread per item; float4 vector loads/stores.

__global__ __launch_bounds__(256) void fp16_to_fp8_pulse_kernel(
    const float4* __restrict__ in,   // 4 x float4 per item
    float4* __restrict__ out,        // 2 x float4 per item
    int n_items)
{
    int i = blockIdx.x * blockDim.x + threadIdx.x;
    if (i >= n_items) return;

    const float4 v0 = in[4 * i + 0];
    const float4 v1 = in[4 * i + 1];
    const float4 v2 = in[4 * i + 2];
    const float4 v3 = in[4 * i + 3];

    // bits are exactly 0.0f or 1.0f
    const int b0  = v0.x > 0.5f;  // sign
    const int b1  = v0.y > 0.5f;  // e4
    const int b2  = v0.z > 0.5f;  // e3
    const int b3  = v0.w > 0.5f;  // e2
    const int b4  = v1.x > 0.5f;  // e1
    const int b5  = v1.y > 0.5f;  // e0
    const int b6  = v1.z > 0.5f;  // m9
    const int b7  = v1.w > 0.5f;  // m8
    const int b8  = v2.x > 0.5f;  // m7
    const int b9  = v2.y > 0.5f;  // m6
    const int b10 = v2.z > 0.5f;  // m5
    const int b11 = v2.w > 0.5f;  // m4
    const int b12 = v3.x > 0.5f;  // m3
    const int b13 = v3.y > 0.5f;  // m2
    const int b14 = v3.z > 0.5f;  // m1
    const int b15 = v3.w > 0.5f;  // m0

    const int s = b0;
    const int e = (b1 << 4) | (b2 << 3) | (b3 << 2) | (b4 << 1) | b5;
    const int m = (b6 << 9) | (b7 << 8) | (b8 << 7) | (b9 << 6) | (b10 << 5) |
                  (b11 << 4) | (b12 << 3) | (b13 << 2) | (b14 << 1) | b15;

    // --- normal path: RNE((m) >> 7), exponent bump on mantissa carry
    {
        // computed unconditionally; selected below
    }
    const int keep_n   = m >> 7;
    const int rbit_n   = (m >> 6) & 1;
    const int sticky_n = (m & 63) ? 1 : 0;
    const int mant_r   = keep_n + (rbit_n & (sticky_n | (keep_n & 1)));
    const int norm_e   = (e - 8) + (mant_r >> 3);
    const int norm_m   = mant_r & 7;

    // --- subnormal path: RNE((1024 + m) >> clip(16-e, 8, 11))
    int k = 16 - e;
    k = k < 8 ? 8 : (k > 11 ? 11 : k);
    const int x        = 1024 + m;
    const int keep_s   = x >> k;
    const int rbit_s   = (x >> (k - 1)) & 1;
    const int lowmask  = (1 << (k - 1)) - 1;
    const int sticky_s = (x & lowmask) ? 1 : 0;
    const int m_sub    = keep_s + (rbit_s & (sticky_s | (keep_s & 1)));
    const int sub_e    = m_sub >> 3;
    const int sub_m    = (m_sub >= 8) ? 0 : m_sub;

    // --- select
    int out_e, out_m;
    if (e > 22)      { out_e = 15;     out_m = 6;      }
    else if (e < 5)  { out_e = 0;      out_m = 0;      }
    else if (e <= 8) { out_e = sub_e;  out_m = sub_m;  }
    else             { out_e = norm_e; out_m = norm_m; }

    float4 o0, o1;
    o0.x = (float)s;
    o0.y = (float)((out_e >> 3) & 1);
    o0.z = (float)((out_e >> 2) & 1);
    o0.w = (float)((out_e >> 1) & 1);
    o1.x = (float)(out_e & 1);
    o1.y = (float)((out_m >> 2) & 1);
    o1.z = (float)((out_m >> 1) & 1);
    o1.w = (float)(out_m & 1);

    out[2 * i + 0] = o0;
    out[2 * i + 1] = o1;
}

extern "C" void kernel_launch(void* const* d_in, const int* in_sizes, int n_in,
                              void* d_out, int out_size, void* d_ws, size_t ws_size,
                              hipStream_t stream) {
    const float4* in = (const float4*)d_in[0];
    float4* out = (float4*)d_out;

    const int n_items = in_sizes[0] / 16;          // 4096*4096 = 16,777,216
    const int block = 256;
    const int grid = (n_items + block - 1) / block; // 65536

    fp16_to_fp8_pulse_kernel<<<grid, block, 0, stream>>>(in, out, n_items);
}